// Round 14
// baseline (153.328 us; speedup 1.0000x reference)
//
#include <hip/hip_runtime.h>

// OmniShift collapsed to one effective 5x5 depthwise conv per channel.
// x: (8, 192, 256, 256) fp32. 805 MB min traffic.
//
// R14 = R13 (149.9us) with TR 32->64 via 512-thread blocks.
//  Per-WAVE staging + compute identical to R13 (8 output rows/wave, ~9 DMAs/
//  thread); occupancy unchanged (2 blk/CU x 8 waves = 16 waves/CU; LDS
//  71.8KB x2 = 143.6KB <= 160KB). Vertical halo 12.5% -> 6.25% (~22MB fetch,
//  ~4us). Swizzle kept (6144 %8 == 0 -> bijective).
// Lessons kept: no min-waves launch_bounds (R5/R9/R10), no nt stores (R3),
// readfirstlane via bit_cast (R8), coarse stage->sync->compute (R12),
// DMA staging global_load_lds w=16 (R11).

typedef float f32x2 __attribute__((ext_vector_type(2)));
typedef float f32x4 __attribute__((ext_vector_type(4)));

constexpr int Bn = 8, Cn = 192, Hn = 256, Wn = 256;
constexpr int TR      = 64;          // output rows per block
constexpr int LROWS   = TR + 4;      // 68 staged rows
constexpr int LSTRIDE = 264;         // 4 + 256 + 4 f32; data col w at pos w+4
constexpr int BANDS   = Hn / TR;     // 4
constexpr int NWG     = Bn * Cn * BANDS;   // 6144; %8==0 -> swizzle bijective
constexpr int CHUNK   = NWG / 8;           // 768 blocks per XCD
constexpr int NTHR    = 512;               // 8 waves

__device__ __forceinline__ float uniformf(float v) {
    return __builtin_bit_cast(float,
        __builtin_amdgcn_readfirstlane(__builtin_bit_cast(int, v)));
}

__device__ __forceinline__ void gload16(const float* g, float* l) {
    __builtin_amdgcn_global_load_lds(
        (const __attribute__((address_space(1))) unsigned int*)g,
        (__attribute__((address_space(3))) unsigned int*)l, 16, 0, 0);
}

__global__ __launch_bounds__(NTHR)
void omnishift_kernel(const float* __restrict__ x,
                      const float* __restrict__ w1,
                      const float* __restrict__ w3,
                      const float* __restrict__ w5,
                      const float* __restrict__ alpha,
                      float* __restrict__ out)
{
    __shared__ float lds[LROWS * LSTRIDE];   // 71808 B -> 2 blocks/CU

    const int tid   = threadIdx.x;
    // XCD swizzle: contiguous chunk per XCD -> band/plane neighbors share L2.
    const int wg    = (blockIdx.x & 7) * CHUNK + (blockIdx.x >> 3);
    const int band  = wg % BANDS;
    const int plane = wg / BANDS;            // b*C + c
    const int c     = plane % Cn;
    const int r0    = band * TR;

    // ---- effective 5x5 weights (block-uniform -> SGPRs) ----
    const float a0 = alpha[0], a1 = alpha[1], a2 = alpha[2], a3 = alpha[3];
    float wf[5][5];
#pragma unroll
    for (int i = 0; i < 5; ++i)
#pragma unroll
        for (int j = 0; j < 5; ++j) {
            float v = a3 * w5[(c * 5 + i) * 5 + j];
            if (i >= 1 && i <= 3 && j >= 1 && j <= 3)
                v += a2 * w3[(c * 3 + (i - 1)) * 3 + (j - 1)];
            if (i == 2 && j == 2)
                v += a1 * w1[c] + a0;
            wf[i][j] = uniformf(v);
        }

    const float* xp = x + (size_t)plane * (Hn * Wn);

    // ---- zero halo cols: pos 2,3 (cols -2,-1), 260,261 (cols 256,257) ----
    if (tid < LROWS * 4) {
        const int r   = tid >> 2;
        const int q   = tid & 3;
        const int pos = (q < 2) ? (2 + q) : (258 + q);
        lds[r * LSTRIDE + pos] = 0.f;
    }

    // ---- stage 68 rows via HBM->LDS DMA (9 issues/thread, last masked) ----
#pragma unroll
    for (int i = 0; i < 9; ++i) {
        const int idx = tid + i * NTHR;      // 0..4607; need 0..4351 (68 rows*64)
        const int row = idx >> 6;            // wave-uniform
        const int l   = idx & 63;            // lane id
        if (row < LROWS) {                   // wave-uniform mask
            const int gr = r0 - 2 + row;
            float* dst = &lds[row * LSTRIDE + 4];     // uniform base; HW adds lane*16
            if ((unsigned)gr < (unsigned)Hn) {
                gload16(xp + (size_t)gr * Wn + 4 * l, dst);
            } else {
                f32x2 z = {0.f, 0.f};
                f32x2* d = reinterpret_cast<f32x2*>(dst + 4 * l);
                d[0] = z; d[1] = z;
            }
        }
    }
    __syncthreads();   // drains DMA (vmcnt) + lgkm -> tile complete

    // ---- compute: wave = 8 rows; thread = 4-col strip, 5x8 sliding window ----
    const int ct     = tid & 63;
    const int rg     = tid >> 6;     // 0..7
    const int oc0    = 4 * ct;
    const int lrbase = rg * 8;

    float* outp = out + (size_t)plane * (Hn * Wn)
                      + (size_t)(r0 + rg * 8) * Wn + oc0;

    // window row = cols oc0-2..oc0+5 = pos oc0+2..oc0+9: 4x ds_read_b64
    auto ldrow = [&](int lr, float w[8]) {
        const f32x2* src = reinterpret_cast<const f32x2*>(
            &lds[lr * LSTRIDE + oc0 + 2]);           // byte 8-aligned
#pragma unroll
        for (int h = 0; h < 4; ++h) {
            f32x2 p = src[h];
            w[2 * h] = p.x; w[2 * h + 1] = p.y;
        }
    };

    float win[5][8];
#pragma unroll
    for (int i = 0; i < 4; ++i) ldrow(lrbase + i, win[i]);

#pragma unroll
    for (int k = 0; k < 8; ++k) {
        ldrow(lrbase + 4 + k, win[4]);

        f32x4 o;
#pragma unroll
        for (int j = 0; j < 4; ++j) {
            float acc = 0.f;
#pragma unroll
            for (int i = 0; i < 5; ++i)
#pragma unroll
                for (int d = 0; d < 5; ++d)
                    acc += win[i][j + d] * wf[i][d];
            o[j] = acc;
        }
        *reinterpret_cast<f32x4*>(outp + (size_t)k * Wn) = o;

#pragma unroll
        for (int i = 0; i < 4; ++i)
#pragma unroll
            for (int j = 0; j < 8; ++j) win[i][j] = win[i + 1][j];
    }
}

extern "C" void kernel_launch(void* const* d_in, const int* in_sizes, int n_in,
                              void* d_out, int out_size, void* d_ws, size_t ws_size,
                              hipStream_t stream)
{
    const float* x     = (const float*)d_in[0];
    const float* w1    = (const float*)d_in[1];
    const float* w3    = (const float*)d_in[2];
    const float* w5    = (const float*)d_in[3];
    const float* alpha = (const float*)d_in[4];
    float* out = (float*)d_out;

    omnishift_kernel<<<NWG, NTHR, 0, stream>>>(x, w1, w3, w5, alpha, out);
}

// Round 15
// 152.418 us; speedup vs baseline: 1.0060x; 1.0060x over previous
//
#include <hip/hip_runtime.h>

// OmniShift collapsed to one effective 5x5 depthwise conv per channel.
// x: (8, 192, 256, 256) fp32. 805 MB min traffic.
//
// R15 = R13 + coarse double-buffer with counted vmcnt (T4 at TILE granularity,
// not R12's fine 8-row phases which regressed).
//  Block = 2 stacked 32-row tiles, 2 LDS buffers (78KB -> 2 blocks/CU).
//  stage(buf0); stage(buf1); [vmcnt(9);bar] compute0; [vmcnt(8);bar] compute1.
//  buf1's DMAs and tile0's stores stay in flight across barriers -> removes
//  the per-tile vmcnt(0) drain bubble (~1.3us/CU-round = the 14us gap to the
//  copy-rate floor).
//  Counted waits need EQUAL VMEM counts per wave: OOB rows DMA a clamped row
//  into a dummy LDS row + ds_write zeros to the real row (never skip the DMA).
// Lessons kept: no min-waves launch_bounds (R5/R9/R10), no nt stores (R3),
// readfirstlane via bit_cast (R8), DMA staging w=16 (R11), XCD swizzle (R13).

typedef float f32x2 __attribute__((ext_vector_type(2)));
typedef float f32x4 __attribute__((ext_vector_type(4)));

constexpr int Bn = 8, Cn = 192, Hn = 256, Wn = 256;
constexpr int TR      = 32;          // output rows per tile
constexpr int LROWS   = TR + 4;      // 36 staged rows per tile
constexpr int LSTRIDE = 264;         // 4 + 256 + 4 f32; data col w at pos w+4
constexpr int BROWS   = LROWS + 1;   // +1 dummy row for OOB-equalizing DMAs
constexpr int PAIRS   = Hn / (2 * TR);           // 4 tile-pairs per plane
constexpr int NWG     = Bn * Cn * PAIRS;         // 6144; %8==0 -> bijective
constexpr int CHUNK   = NWG / 8;                 // 768 blocks per XCD

__device__ __forceinline__ float uniformf(float v) {
    return __builtin_bit_cast(float,
        __builtin_amdgcn_readfirstlane(__builtin_bit_cast(int, v)));
}

__device__ __forceinline__ void gload16(const float* g, float* l) {
    __builtin_amdgcn_global_load_lds(
        (const __attribute__((address_space(1))) unsigned int*)g,
        (__attribute__((address_space(3))) unsigned int*)l, 16, 0, 0);
}

__global__ __launch_bounds__(256)
void omnishift_kernel(const float* __restrict__ x,
                      const float* __restrict__ w1,
                      const float* __restrict__ w3,
                      const float* __restrict__ w5,
                      const float* __restrict__ alpha,
                      float* __restrict__ out)
{
    __shared__ float lds[2][BROWS * LSTRIDE];   // 78144 B -> 2 blocks/CU

    const int tid   = threadIdx.x;
    // XCD swizzle: contiguous chunk per XCD -> neighbors share that XCD's L2.
    const int wg    = (blockIdx.x & 7) * CHUNK + (blockIdx.x >> 3);
    const int bb    = wg & 3;
    const int plane = wg >> 2;               // b*C + c
    const int c     = plane % Cn;
    const int r0    = bb * 2 * TR;           // block covers rows r0 .. r0+63

    // ---- effective 5x5 weights (block-uniform -> SGPRs) ----
    const float a0 = alpha[0], a1 = alpha[1], a2 = alpha[2], a3 = alpha[3];
    float wf[5][5];
#pragma unroll
    for (int i = 0; i < 5; ++i)
#pragma unroll
        for (int j = 0; j < 5; ++j) {
            float v = a3 * w5[(c * 5 + i) * 5 + j];
            if (i >= 1 && i <= 3 && j >= 1 && j <= 3)
                v += a2 * w3[(c * 3 + (i - 1)) * 3 + (j - 1)];
            if (i == 2 && j == 2)
                v += a1 * w1[c] + a0;
            wf[i][j] = uniformf(v);
        }

    const float* xp = x   + (size_t)plane * (Hn * Wn);
    float*       op = out + (size_t)plane * (Hn * Wn);

    // ---- zero halo cols of both buffers (pos 2,3 and 260,261) ----
#pragma unroll
    for (int b = 0; b < 2; ++b)
        if (tid < LROWS * 4) {
            const int r   = tid >> 2;
            const int q   = tid & 3;
            const int pos = (q < 2) ? (2 + q) : (258 + q);
            lds[b][r * LSTRIDE + pos] = 0.f;
        }

    // ---- stage one 36-row tile into buf b; EXACTLY 9 DMAs per thread ----
    auto stage = [&](const int b, const int base) {
#pragma unroll
        for (int i = 0; i < 9; ++i) {
            const int idx = tid + i * 256;   // 0..2303 = 36 rows * 64 lanes
            const int row = idx >> 6;        // wave-uniform
            const int l   = idx & 63;
            const int gr  = base - 2 + row;
            if ((unsigned)gr < (unsigned)Hn) {
                gload16(xp + (size_t)gr * Wn + 4 * l,
                        &lds[b][row * LSTRIDE + 4]);
            } else {
                // keep VMEM count equal: DMA a valid row into the dummy slot,
                // and put the required zeros in the real row via ds_write.
                gload16(xp + 4 * l, &lds[b][LROWS * LSTRIDE + 4]);
                f32x2 z = {0.f, 0.f};
                f32x2* d = reinterpret_cast<f32x2*>(
                    &lds[b][row * LSTRIDE + 4 + 4 * l]);
                d[0] = z; d[1] = z;
            }
        }
    };

    // ---- compute one 32-row tile from buf b (R13 sliding window) ----
    const int ct     = tid & 63;
    const int rg     = tid >> 6;
    const int oc0    = 4 * ct;
    const int lrbase = rg * 8;

    auto compute = [&](const int b, const int rt) {
        const float* buf = lds[b];
        auto ldrow = [&](int lr, float w[8]) {
            const f32x2* src = reinterpret_cast<const f32x2*>(
                &buf[lr * LSTRIDE + oc0 + 2]);       // byte 8-aligned
#pragma unroll
            for (int h = 0; h < 4; ++h) {
                f32x2 p = src[h];
                w[2 * h] = p.x; w[2 * h + 1] = p.y;
            }
        };

        float* outp = op + (size_t)(rt + rg * 8) * Wn + oc0;

        float win[5][8];
#pragma unroll
        for (int i = 0; i < 4; ++i) ldrow(lrbase + i, win[i]);

#pragma unroll
        for (int k = 0; k < 8; ++k) {
            ldrow(lrbase + 4 + k, win[4]);

            f32x4 o;
#pragma unroll
            for (int j = 0; j < 4; ++j) {
                float acc = 0.f;
#pragma unroll
                for (int i = 0; i < 5; ++i)
#pragma unroll
                    for (int d = 0; d < 5; ++d)
                        acc += win[i][j + d] * wf[i][d];
                o[j] = acc;
            }
            *reinterpret_cast<f32x4*>(outp + (size_t)k * Wn) = o;

#pragma unroll
            for (int i = 0; i < 4; ++i)
#pragma unroll
                for (int j = 0; j < 8; ++j) win[i][j] = win[i + 1][j];
        }
    };

    // ---- schedule: dbuf with counted vmcnt; never drain to 0 mid-block ----
    stage(0, r0);            // 9 DMAs
    stage(1, r0 + TR);       // 9 DMAs  (18 outstanding)
    // buf0 ready: allow buf1's 9 newest to remain in flight; halo/OOB zeros drained
    asm volatile("s_waitcnt vmcnt(9) lgkmcnt(0)\n\ts_barrier" ::: "memory");
    compute(0, r0);          // 8 stores
    // buf1 ready: allow the 8 stores to remain in flight
    asm volatile("s_waitcnt vmcnt(8) lgkmcnt(0)\n\ts_barrier" ::: "memory");
    compute(1, r0 + TR);
}

extern "C" void kernel_launch(void* const* d_in, const int* in_sizes, int n_in,
                              void* d_out, int out_size, void* d_ws, size_t ws_size,
                              hipStream_t stream)
{
    const float* x     = (const float*)d_in[0];
    const float* w1    = (const float*)d_in[1];
    const float* w3    = (const float*)d_in[2];
    const float* w5    = (const float*)d_in[3];
    const float* alpha = (const float*)d_in[4];
    float* out = (float*)d_out;

    omnishift_kernel<<<NWG, 256, 0, stream>>>(x, w1, w3, w5, alpha, out);
}

// Round 16
// 148.998 us; speedup vs baseline: 1.0291x; 1.0230x over previous
//
#include <hip/hip_runtime.h>

// OmniShift collapsed to one effective 5x5 depthwise conv per channel.
// x: (8, 192, 256, 256) fp32. 805 MB min traffic.
//
// FINAL = R13 (best: 149.9us = 5.71 TB/s effective, 91% of copy-ubench).
//  - Effective-weight collapse: a0*x + a1*dw1 + a2*dw3 + a3*dw5 == one 5x5
//    depthwise conv (weights built per-block into SGPRs).
//  - 36-row tile staged via global_load_lds w=16 DMA (no dest VGPRs; broke
//    the 157us reg-staging plateau: R11).
//  - Coarse stage-all -> syncthreads -> compute-all (fine phasing regressed:
//    R12 163.5; dbuf counted-vmcnt regressed: R15 152.4; TR=64: R14 153.3).
//  - XCD-chunked swizzle: band-adjacent blocks share an XCD L2 (R13: -1.1us).
//  - 5x8 sliding register window, 4x ds_read_b64/row, f32x4 stores.
// Lessons: no min-waves launch_bounds (spills: R5/R9/R10), no nt stores (R3),
// readfirstlane via bit_cast (R8: float arg silently fptosi-converts!).

typedef float f32x2 __attribute__((ext_vector_type(2)));
typedef float f32x4 __attribute__((ext_vector_type(4)));

constexpr int Bn = 8, Cn = 192, Hn = 256, Wn = 256;
constexpr int TR      = 32;          // output rows per block
constexpr int LROWS   = TR + 4;      // 36 staged rows
constexpr int LSTRIDE = 264;         // 4 + 256 + 4 f32; data col w at pos w+4
constexpr int BANDS   = Hn / TR;     // 8
constexpr int NWG     = Bn * Cn * BANDS;   // 12288; %8==0 -> swizzle bijective
constexpr int CHUNK   = NWG / 8;           // 1536 blocks per XCD

__device__ __forceinline__ float uniformf(float v) {
    return __builtin_bit_cast(float,
        __builtin_amdgcn_readfirstlane(__builtin_bit_cast(int, v)));
}

__device__ __forceinline__ void gload16(const float* g, float* l) {
    __builtin_amdgcn_global_load_lds(
        (const __attribute__((address_space(1))) unsigned int*)g,
        (__attribute__((address_space(3))) unsigned int*)l, 16, 0, 0);
}

__global__ __launch_bounds__(256)
void omnishift_kernel(const float* __restrict__ x,
                      const float* __restrict__ w1,
                      const float* __restrict__ w3,
                      const float* __restrict__ w5,
                      const float* __restrict__ alpha,
                      float* __restrict__ out)
{
    __shared__ float lds[LROWS * LSTRIDE];   // 38016 B -> 4 blocks/CU

    const int tid   = threadIdx.x;
    // XCD swizzle: dispatcher round-robins blockIdx across 8 XCDs; remap so
    // each XCD gets a contiguous chunk -> band-adjacent blocks share its L2.
    const int wg    = (blockIdx.x & 7) * CHUNK + (blockIdx.x >> 3);
    const int band  = wg % BANDS;
    const int plane = wg / BANDS;            // b*C + c
    const int c     = plane % Cn;
    const int r0    = band * TR;

    // ---- effective 5x5 weights (block-uniform -> SGPRs) ----
    const float a0 = alpha[0], a1 = alpha[1], a2 = alpha[2], a3 = alpha[3];
    float wf[5][5];
#pragma unroll
    for (int i = 0; i < 5; ++i)
#pragma unroll
        for (int j = 0; j < 5; ++j) {
            float v = a3 * w5[(c * 5 + i) * 5 + j];
            if (i >= 1 && i <= 3 && j >= 1 && j <= 3)
                v += a2 * w3[(c * 3 + (i - 1)) * 3 + (j - 1)];
            if (i == 2 && j == 2)
                v += a1 * w1[c] + a0;
            wf[i][j] = uniformf(v);
        }

    const float* xp = x + (size_t)plane * (Hn * Wn);

    // ---- zero halo cols: pos 2,3 (cols -2,-1), 260,261 (cols 256,257) ----
    if (tid < LROWS * 4) {
        const int r   = tid >> 2;
        const int q   = tid & 3;
        const int pos = (q < 2) ? (2 + q) : (258 + q);
        lds[r * LSTRIDE + pos] = 0.f;
    }

    // ---- stage 36 rows via HBM->LDS DMA (9 issues/thread, no dest regs) ----
#pragma unroll
    for (int i = 0; i < 9; ++i) {
        const int idx = tid + i * 256;       // 0..2303 = 36 rows * 64 lanes
        const int row = idx >> 6;            // wave-uniform
        const int l   = idx & 63;            // lane id
        const int gr  = r0 - 2 + row;
        float* dst = &lds[row * LSTRIDE + 4];         // uniform base; HW adds lane*16
        if ((unsigned)gr < (unsigned)Hn) {
            gload16(xp + (size_t)gr * Wn + 4 * l, dst);
        } else {
            f32x2 z = {0.f, 0.f};
            f32x2* d = reinterpret_cast<f32x2*>(dst + 4 * l);
            d[0] = z; d[1] = z;
        }
    }
    __syncthreads();   // drains DMA (vmcnt) + lgkm -> tile complete

    // ---- compute: thread = 4-col strip x 8 rows, 5x8 sliding window ----
    const int ct     = tid & 63;
    const int rg     = tid >> 6;
    const int oc0    = 4 * ct;
    const int lrbase = rg * 8;

    float* outp = out + (size_t)plane * (Hn * Wn)
                      + (size_t)(r0 + rg * 8) * Wn + oc0;

    // window row = cols oc0-2..oc0+5 = pos oc0+2..oc0+9: 4x ds_read_b64
    auto ldrow = [&](int lr, float w[8]) {
        const f32x2* src = reinterpret_cast<const f32x2*>(
            &lds[lr * LSTRIDE + oc0 + 2]);           // byte 8-aligned
#pragma unroll
        for (int h = 0; h < 4; ++h) {
            f32x2 p = src[h];
            w[2 * h] = p.x; w[2 * h + 1] = p.y;
        }
    };

    float win[5][8];
#pragma unroll
    for (int i = 0; i < 4; ++i) ldrow(lrbase + i, win[i]);

#pragma unroll
    for (int k = 0; k < 8; ++k) {
        ldrow(lrbase + 4 + k, win[4]);

        f32x4 o;
#pragma unroll
        for (int j = 0; j < 4; ++j) {
            float acc = 0.f;
#pragma unroll
            for (int i = 0; i < 5; ++i)
#pragma unroll
                for (int d = 0; d < 5; ++d)
                    acc += win[i][j + d] * wf[i][d];
            o[j] = acc;
        }
        *reinterpret_cast<f32x4*>(outp + (size_t)k * Wn) = o;

#pragma unroll
        for (int i = 0; i < 4; ++i)
#pragma unroll
            for (int j = 0; j < 8; ++j) win[i][j] = win[i + 1][j];
    }
}

extern "C" void kernel_launch(void* const* d_in, const int* in_sizes, int n_in,
                              void* d_out, int out_size, void* d_ws, size_t ws_size,
                              hipStream_t stream)
{
    const float* x     = (const float*)d_in[0];
    const float* w1    = (const float*)d_in[1];
    const float* w3    = (const float*)d_in[2];
    const float* w5    = (const float*)d_in[3];
    const float* alpha = (const float*)d_in[4];
    float* out = (float*)d_out;

    omnishift_kernel<<<NWG, 256, 0, stream>>>(x, w1, w3, w5, alpha, out);
}